// Round 8
// baseline (957.503 us; speedup 1.0000x reference)
//
#include <hip/hip_runtime.h>
#include <hip/hip_bf16.h>

// GraphNetwork GAT: B=4, N=2048, I=32, H=64, O=32, E=2, HD=2, D1=256
// R14: 7 dispatches (prep, [wh_a, stats, mac] x2). scale/combine fused into
// stats via atomic S + last-block-per-(b,jt) scales WhB in place. out fused
// into mac<1> via atomic acc + last-block-per-b matvec. prep zeroes S/cnt/
// acc/cnt2; mac<0> re-zeroes S/cnt for layer 1. Compute bodies = R11
// (verified 372.8us): async global_load_lds edge staging, XOR-swizzled LDS,
// denominator pre-folded into WhB, log2-domain softmax.

constexpr int B_  = 4;
constexpr int N_  = 2048;
constexpr int I_  = 32;
constexpr int H_  = 64;
constexpr int O_  = 32;
constexpr int EH_ = 4;          // E*HD combos, c = e*2 + h
constexpr int D1_ = 256;        // H*HD*E
constexpr int BN_ = B_ * N_;    // 8192
constexpr int NC_ = 64;         // i-chunks for softmax stats (CH=32)
constexpr int JT_ = 8;          // j-tiles of 256
constexpr int TI_ = 16;         // msg rows per block (one MFMA m-tile)
constexpr int TK_ = 32;         // k-tile (one MFMA K)
constexpr int NST_ = 32;        // steps per mac block (each kh-wave: 1 kt/step)

typedef __bf16 bf16x8 __attribute__((ext_vector_type(8)));
typedef float floatx4 __attribute__((ext_vector_type(4)));

constexpr float L2E_ = 1.4426950408889634f;   // log2(e)

__device__ __forceinline__ unsigned short f2b(float f) {
    unsigned int u = __float_as_uint(f);
    return (unsigned short)((u + 0x7fffu + ((u >> 16) & 1u)) >> 16);
}

__device__ __forceinline__ float fexp2(float x) {
#if __has_builtin(__builtin_amdgcn_exp2f)
    return __builtin_amdgcn_exp2f(x);      // v_exp_f32 (exp2) direct
#else
    return __expf(x * 0.6931471805599453f);
#endif
}

// async global->LDS 16B per lane; dest = wave-uniform base + lane*16
__device__ __forceinline__ void gl2lds16(const void* g, void* l) {
    __builtin_amdgcn_global_load_lds(
        (const __attribute__((address_space(1))) unsigned int*)g,
        (__attribute__((address_space(3))) unsigned int*)l, 16, 0, 0);
}

// ------------------------------------------------- fused preprocessing
// blocks [0,2048): embed; [2048,2112): pack Wf0; [2112,2368): pack Wf1.
// Also zeroes S/cnt/acc/cnt2 (grid-stride by global thread id).
__global__ __launch_bounds__(256) void prep_kernel(
        const float* __restrict__ nodes, const float* __restrict__ W_emb,
        const float* __restrict__ b_emb, const float* __restrict__ Wf0,
        const float* __restrict__ Wf1, unsigned short* __restrict__ state0B,
        unsigned short* __restrict__ WfB0, unsigned short* __restrict__ WfB1,
        float* __restrict__ S, unsigned int* __restrict__ cnt,
        float* __restrict__ acc, unsigned int* __restrict__ cnt2) {
    int blk = blockIdx.x;
    int t = threadIdx.x;
    int gt = blk * 256 + t;
    if (gt < EH_ * BN_) S[gt] = 0.f;
    if (gt < B_ * JT_) cnt[gt] = 0u;
    if (gt < B_ * H_) acc[gt] = 0.f;
    if (gt < B_) cnt2[gt] = 0u;

    __shared__ float sn[4][I_];
    if (blk < 2048) {
        int r = t >> 6, h = t & 63;
        if (t < 4 * I_) {
            int rr = t / I_, ii = t % I_;
            sn[rr][ii] = nodes[(size_t)(blk * 4 + rr) * I_ + ii];
        }
        __syncthreads();
        float a = b_emb[h];
        #pragma unroll
        for (int i = 0; i < I_; ++i) a += sn[r][i] * W_emb[i * H_ + h];
        state0B[(size_t)(blk * 4 + r) * H_ + h] = f2b(a);
    } else if (blk < 2048 + 64) {
        int o = (blk - 2048) * 256 + t;         // din=64
        int k = o & 63, n = (o >> 6) & 63, c = o >> 12;
        WfB0[o] = f2b(Wf0[((size_t)c * 64 + k) * 64 + n]);
    } else {
        int o = (blk - 2112) * 256 + t;         // din=256
        int k = o & 255, n = (o >> 8) & 63, c = o >> 14;
        WfB1[o] = f2b(Wf1[((size_t)c * 256 + k) * 64 + n]);
    }
}

// ---------------------------------------------------- Wh + a1/a2 via MFMA
// a1/a2 outputs are PRE-SCALED by log2(e) for the log2-domain softmax.
template <int DIN>
__global__ __launch_bounds__(256) void wh_a_mfma_kernel(
        const unsigned short* __restrict__ stateB, const unsigned short* __restrict__ WfB,
        const float* __restrict__ w1, const float* __restrict__ b1,
        const float* __restrict__ w2, const float* __restrict__ b2,
        unsigned short* __restrict__ WhB, float* __restrict__ a1,
        float* __restrict__ a2) {
    int t = threadIdx.x;
    int lane = t & 63, wv = t >> 6;             // wv = c
    int col = lane & 15, qd = lane >> 4;
    int bn0 = blockIdx.x * TI_;                 // grid BN/16 = 512
    int b = bn0 >> 11;

    floatx4 acc[4] = {{0,0,0,0},{0,0,0,0},{0,0,0,0},{0,0,0,0}};
    const unsigned short* __restrict__ ap = stateB + (size_t)(bn0 + col) * DIN + qd * 8;
    const unsigned short* __restrict__ bp = WfB + ((size_t)(wv * 64 + col) * DIN + qd * 8);
    #pragma unroll
    for (int k0 = 0; k0 < DIN; k0 += 32) {
        bf16x8 af = *(const bf16x8*)(ap + k0);
        #pragma unroll
        for (int nt = 0; nt < 4; ++nt) {
            bf16x8 bf = *(const bf16x8*)(bp + (size_t)nt * 16 * DIN + k0);
            acc[nt] = __builtin_amdgcn_mfma_f32_16x16x32_bf16(af, bf, acc[nt], 0, 0, 0);
        }
    }
    // acc[nt][r] = Wh[bn0 + qd*4 + r][nt*16 + col]
    int nb = ((bn0 & 2047) >> 3) + (qd >> 1);
    #pragma unroll
    for (int nt = 0; nt < 4; ++nt) {
        unsigned int lo = (unsigned int)f2b(acc[nt][0]) | ((unsigned int)f2b(acc[nt][1]) << 16);
        unsigned int hi = (unsigned int)f2b(acc[nt][2]) | ((unsigned int)f2b(acc[nt][3]) << 16);
        uint2 v = make_uint2(lo, hi);
        *(uint2*)(WhB + ((((size_t)(wv * B_ + b) * 256 + nb) * 64 + nt * 16 + col) * 8
                         + (qd & 1) * 4)) = v;
    }
    // a1/a2 row dots, butterfly over col lanes
    float p1[4] = {}, p2[4] = {};
    #pragma unroll
    for (int nt = 0; nt < 4; ++nt) {
        float w1n = w1[wv * H_ + nt * 16 + col];
        float w2n = w2[wv * H_ + nt * 16 + col];
        #pragma unroll
        for (int r = 0; r < 4; ++r) {
            p1[r] += acc[nt][r] * w1n;
            p2[r] += acc[nt][r] * w2n;
        }
    }
    #pragma unroll
    for (int m = 1; m < 16; m <<= 1)
        #pragma unroll
        for (int r = 0; r < 4; ++r) {
            p1[r] += __shfl_xor(p1[r], m, 64);
            p2[r] += __shfl_xor(p2[r], m, 64);
        }
    if (col == 0) {
        float b1c = b1[wv], b2c = b2[wv];
        #pragma unroll
        for (int r = 0; r < 4; ++r) {
            a1[(size_t)wv * BN_ + bn0 + qd * 4 + r] = (p1[r] + b1c) * L2E_;
            a2[(size_t)wv * BN_ + bn0 + qd * 4 + r] = (p2[r] + b2c) * L2E_;
        }
    }
}

// ---------------------- column softmax stats + fused denominator fold
// Grid B*NC*JT = 2048, 256 thr. Block (b,ic,jt): i in [ic*32,ic*32+32),
// j = jt*256 + t. Partial sums atomicAdd'ed into S[c][bn]; the LAST block
// of each (b,jt) group (counter) inverts S and scales WhB[all c][b][k-range]
// in place (k-range = [jt*256, jt*256+256)).
__global__ __launch_bounds__(256) void stats_kernel(
        const float* __restrict__ edges, const float* __restrict__ a1,
        const float* __restrict__ a2, float* __restrict__ S,
        unsigned int* __restrict__ cnt, unsigned short* __restrict__ WhB) {
    int blk = blockIdx.x;
    int jt = blk & 7;
    int ic = (blk >> 3) & 63;
    int b  = blk >> 9;
    int t = threadIdx.x;
    int j = jt * 256 + t;
    __shared__ float sa1[EH_][32];
    __shared__ float sInv[EH_][256];
    __shared__ unsigned int sflag;
    if (t < 128) {
        int cc = t >> 5, ii = t & 31;
        sa1[cc][ii] = a1[(size_t)cc * BN_ + b * N_ + ic * 32 + ii];
    }
    __syncthreads();
    float a2v[EH_], s[EH_];
    #pragma unroll
    for (int cc = 0; cc < EH_; ++cc) {
        a2v[cc] = a2[(size_t)cc * BN_ + b * N_ + j];
        s[cc] = 0.f;
    }
    const float2* __restrict__ ep =
        (const float2*)edges + (size_t)(b * N_ + ic * 32) * N_ + j;
    #pragma unroll 4
    for (int ii = 0; ii < 32; ++ii) {
        float2 u = ep[(size_t)ii * N_];
        #pragma unroll
        for (int cc = 0; cc < EH_; ++cc) {
            float x = sa1[cc][ii] + a2v[cc];
            float l = fmaxf(x, 0.2f * x);
            s[cc] += fexp2(fmaf((cc < 2) ? u.x : u.y, L2E_, l));
        }
    }
    #pragma unroll
    for (int cc = 0; cc < EH_; ++cc)
        atomicAdd(&S[(size_t)cc * BN_ + b * N_ + j], s[cc]);
    __threadfence();
    __syncthreads();                        // all block atomics complete
    if (t == 0) sflag = atomicAdd(&cnt[b * JT_ + jt], 1u);
    __syncthreads();
    if (sflag == NC_ - 1) {                 // last block of this (b,jt)
        __threadfence();
        for (int q = t; q < EH_ * 256; q += 256) {
            int cc = q >> 8, kk = q & 255;
            float Sv = atomicAdd(&S[(size_t)cc * BN_ + b * N_ + jt * 256 + kk], 0.f);
            sInv[cc][kk] = 1.f / Sv;
        }
        __syncthreads();
        // scale WhB: 4c x 32 nb x 64 ncol uint4 chunks = 8192
        for (int q = t; q < 8192; q += 256) {
            int cc  = q >> 11;
            int nbl = (q >> 6) & 31;
            int ncol = q & 63;
            uint4* wp = (uint4*)WhB
                + (((size_t)(cc * B_ + b) * 256 + jt * 32 + nbl) * 64 + ncol);
            int k0 = nbl * 8;
            uint4 w = *wp;
            unsigned int words[4] = {w.x, w.y, w.z, w.w};
            #pragma unroll
            for (int qq = 0; qq < 4; ++qq) {
                float lo = __uint_as_float((words[qq] & 0xffffu) << 16)
                         * sInv[cc][k0 + 2 * qq];
                float hi = __uint_as_float(words[qq] & 0xffff0000u)
                         * sInv[cc][k0 + 2 * qq + 1];
                words[qq] = (unsigned)f2b(lo) | ((unsigned)f2b(hi) << 16);
            }
            *wp = make_uint4(words[0], words[1], words[2], words[3]);
        }
    }
}

// ------------------------------------------------------------- MFMA MAC
// 8 waves = (c = wv&3, kh = wv>>2). Async DMA edge staging (triple-buffered,
// barrier -> issue s+1 -> compute s), XOR-swizzled source; a2 staged in LDS;
// denominator pre-folded into WhB. Bijective XCD swizzle on blockIdx.
// LAST=0: out = state1B bf16 (+ re-zero S/cnt for layer 1).
// LAST=1: atomic per-b accumulation; last block per b does final matvec.
template <int LAST>
__global__ __launch_bounds__(512, 4) void mac_kernel(
        const float* __restrict__ edges, const float* __restrict__ a1,
        const float* __restrict__ a2s, const unsigned short* __restrict__ WhB,
        const float* __restrict__ bias, void* __restrict__ outv,
        float* __restrict__ Sz, unsigned int* __restrict__ cntz,
        float* __restrict__ accg, unsigned int* __restrict__ cnt2,
        const float* __restrict__ W_out, const float* __restrict__ b_out,
        float* __restrict__ outF) {
    int t = threadIdx.x;                    // 512
    int blk0 = blockIdx.x;                  // hw index, grid 512
    int blk = ((blk0 & 7) << 6) + (blk0 >> 3);   // bijective XCD swizzle
    int b = blk >> 7;
    int i0 = (blk & 127) * TI_;
    int lane = t & 63, wv = t >> 6;
    int c  = wv & 3;                        // edgetype*2 + head
    int kh = wv >> 2;                       // k-half
    int col = lane & 15;                    // i offset (MFMA A row)
    int qd  = lane >> 4;                    // k subgroup (MFMA A k-quad)
    int esel = c >> 1;                      // edge component

    if (!LAST) {                            // re-zero S/cnt for layer 1
        if (t < 64) Sz[(size_t)blk * 64 + t] = 0.f;
        if (blk0 == 0 && t >= 64 && t < 64 + B_ * JT_) cntz[t - 64] = 0u;
    }

    __shared__ float sa2[EH_][N_];                              // 32 KB
    __shared__ __attribute__((aligned(16))) unsigned char eds[3][2][TI_][256]; // 24 KB
    __shared__ float sred[EH_][TI_][H_ + 1];                    // 16.6 KB
    __shared__ unsigned int sflag;
    __shared__ float sacc[H_];

    // stage a2 (pre-scaled by log2e): 4 x N floats, coalesced float4
    for (int q = t; q < EH_ * (N_ / 4); q += 512) {
        int cc = q >> 9, kk = q & 511;
        ((float4*)sa2[cc])[kk] =
            ((const float4*)(a2s + (size_t)cc * BN_ + b * N_))[kk];
    }

    float a1v = a1[(size_t)c * BN_ + b * N_ + i0 + col];          // pre-scaled
    const unsigned short* __restrict__ whb0 = WhB + (size_t)(c * B_ + b) * (N_ * 64);

    // staging role: wave wv stages chunk wv (1KB) of each tile
    int srow  = 4 * (wv & 3) + (lane >> 4);
    int sslot = (lane & 15) ^ (srow & 15);        // pre-swizzled global slot
    const char* gsrc = (const char*)edges
        + ((size_t)(b * N_ + i0 + srow) * N_ + (size_t)(wv >> 2) * 1024) * 8
        + sslot * 16;
    char* ldst = (char*)&eds[0][0][0][0] + wv * 1024;   // + buf*8192 per step

    floatx4 acc[4] = {{0,0,0,0},{0,0,0,0},{0,0,0,0},{0,0,0,0}};

    gl2lds16(gsrc, ldst);                   // stage step 0 -> buf 0
    for (int s = 0; s < NST_; ++s) {
        __syncthreads();                    // publishes stage(s); sa2 on s=0
        if (s + 1 < NST_)                   // async: lands during compute
            gl2lds16(gsrc + (size_t)(s + 1) * 256,
                     ldst + (size_t)(((s + 1) % 3)) * 8192);
        int kt = kh * NST_ + s;
        const unsigned char* ebase = (const unsigned char*)&eds[0][0][0][0]
                          + (s % 3) * 8192 + kh * 4096 + col * 256;
        float ev[8];
        #pragma unroll
        for (int jj = 0; jj < 4; ++jj) {
            int sg = qd * 4 + jj;
            float4 v = *(const float4*)(ebase + ((sg ^ col) * 16));
            ev[2 * jj]     = esel ? v.y : v.x;
            ev[2 * jj + 1] = esel ? v.w : v.z;
        }
        const float4* sp = (const float4*)&sa2[c][kt * TK_ + qd * 8];
        float4 z0 = sp[0], z1 = sp[1];
        float az[8] = {z0.x, z0.y, z0.z, z0.w, z1.x, z1.y, z1.z, z1.w};
        bf16x8 bf[4];
        #pragma unroll
        for (int nt = 0; nt < 4; ++nt)
            bf[nt] = *(const bf16x8*)(whb0 + ((size_t)(kt * 4 + qd) * 64 + nt * 16 + col) * 8);
        bf16x8 af;
        #pragma unroll
        for (int jv = 0; jv < 8; ++jv) {
            float sx = a1v + az[jv];
            float u  = fmaxf(sx, 0.2f * sx);                 // lrelu (log2 dom.)
            af[jv] = (__bf16)fexp2(fmaf(ev[jv], L2E_, u));   // P (unnormalized)
        }
        #pragma unroll
        for (int nt = 0; nt < 4; ++nt)
            acc[nt] = __builtin_amdgcn_mfma_f32_16x16x32_bf16(af, bf[nt], acc[nt], 0, 0, 0);
    }

    // ---- epilogue: acc[nt][r] = msg_partial[i0+qd*4+r][nt*16+col]
    if (kh == 1) {
        #pragma unroll
        for (int nt = 0; nt < 4; ++nt)
            #pragma unroll
            for (int r = 0; r < 4; ++r)
                sred[c][qd * 4 + r][nt * 16 + col] = acc[nt][r];
    }
    __syncthreads();
    if (kh == 0) {
        if (LAST) {
            #pragma unroll
            for (int nt = 0; nt < 4; ++nt) {
                float bb = bias[(c & 1) * H_ + nt * 16 + col];
                #pragma unroll
                for (int r = 0; r < 4; ++r) {
                    float xv = acc[nt][r] + sred[c][qd * 4 + r][nt * 16 + col] + bb;
                    sred[c][qd * 4 + r][nt * 16 + col] =
                        xv > 0.f ? xv : (__expf(xv) - 1.f);  // elu
                }
            }
        } else {
            unsigned short* out = (unsigned short*)outv;
            #pragma unroll
            for (int nt = 0; nt < 4; ++nt) {
                float bb = bias[(c & 1) * H_ + nt * 16 + col];
                #pragma unroll
                for (int r = 0; r < 4; ++r) {
                    float xv = acc[nt][r] + sred[c][qd * 4 + r][nt * 16 + col] + bb;
                    out[((size_t)(b * N_ + i0 + qd * 4 + r)) * D1_ + c * H_ + nt * 16 + col]
                        = f2b(xv);
                }
            }
        }
    }
    if (LAST) {
        __syncthreads();
        // block partial: mean over c, sum over the 16 rows -> atomic acc[b]
        if (t < 64) {
            float s = 0.f;
            #pragma unroll
            for (int r = 0; r < TI_; ++r)
                s += sred[0][r][t] + sred[1][r][t] + sred[2][r][t] + sred[3][r][t];
            atomicAdd(&accg[b * H_ + t], s * 0.25f);
        }
        __threadfence();
        __syncthreads();                    // block atomics complete
        if (t == 0) sflag = atomicAdd(&cnt2[b], 1u);
        __syncthreads();
        if (sflag == 127) {                 // last block of this b
            __threadfence();
            if (t < H_)
                sacc[t] = atomicAdd(&accg[b * H_ + t], 0.f) * (1.f / N_);
            __syncthreads();
            if (t < O_) {
                float o = b_out[t];
                #pragma unroll 8
                for (int dd = 0; dd < H_; ++dd)
                    o += sacc[dd] * W_out[dd * O_ + t];
                outF[b * O_ + t] = o;
            }
        }
    }
}

extern "C" void kernel_launch(void* const* d_in, const int* in_sizes, int n_in,
                              void* d_out, int out_size, void* d_ws, size_t ws_size,
                              hipStream_t stream) {
    const float* nodes = (const float*)d_in[0];
    const float* edges = (const float*)d_in[1];
    const float* W_emb = (const float*)d_in[2];
    const float* b_emb = (const float*)d_in[3];
    const float* Wf0   = (const float*)d_in[4];
    const float* w1_0  = (const float*)d_in[5];
    const float* b1_0  = (const float*)d_in[6];
    const float* w2_0  = (const float*)d_in[7];
    const float* b2_0  = (const float*)d_in[8];
    const float* bias0 = (const float*)d_in[9];
    const float* Wf1   = (const float*)d_in[10];
    const float* w1_1  = (const float*)d_in[11];
    const float* b1_1  = (const float*)d_in[12];
    const float* w2_1  = (const float*)d_in[13];
    const float* b2_1  = (const float*)d_in[14];
    const float* bias1 = (const float*)d_in[15];
    const float* W_out = (const float*)d_in[16];
    const float* b_out = (const float*)d_in[17];

    float* ws = (float*)d_ws;
    unsigned short* state0B = (unsigned short*)ws;                  // 262144 fl
    unsigned short* state1B = (unsigned short*)(ws + 262144);       // 1048576 fl
    unsigned short* WhB  = (unsigned short*)(ws + 1310720);         // 1048576 fl
    unsigned short* WfB0 = (unsigned short*)(ws + 2359296);         // 8192 fl
    unsigned short* WfB1 = (unsigned short*)(ws + 2367488);         // 32768 fl
    float* a1 = ws + 2400256;                                       // 32768 fl
    float* a2 = ws + 2433024;                                       // 32768 fl
    float* S  = ws + 2465792;                                       // 32768 fl
    unsigned int* cnt  = (unsigned int*)(ws + 2498560);             // 32 u
    float* accg        = ws + 2498592;                              // 256 fl
    unsigned int* cnt2 = (unsigned int*)(ws + 2498848);             // 4 u

    prep_kernel<<<2368, 256, 0, stream>>>(nodes, W_emb, b_emb, Wf0, Wf1,
                                          state0B, WfB0, WfB1, S, cnt, accg, cnt2);

    // ---- layer 0
    wh_a_mfma_kernel<H_><<<BN_ / TI_, 256, 0, stream>>>(state0B, WfB0, w1_0, b1_0,
                                                        w2_0, b2_0, WhB, a1, a2);
    stats_kernel<<<B_ * NC_ * JT_, 256, 0, stream>>>(edges, a1, a2, S, cnt, WhB);
    mac_kernel<0><<<B_ * (N_ / TI_), 512, 0, stream>>>(
        edges, a1, a2, WhB, bias0, state1B, S, cnt, accg, cnt2, W_out, b_out,
        (float*)d_out);
    // ---- layer 1
    wh_a_mfma_kernel<D1_><<<BN_ / TI_, 256, 0, stream>>>(state1B, WfB1, w1_1, b1_1,
                                                         w2_1, b2_1, WhB, a1, a2);
    stats_kernel<<<B_ * NC_ * JT_, 256, 0, stream>>>(edges, a1, a2, S, cnt, WhB);
    mac_kernel<1><<<B_ * (N_ / TI_), 512, 0, stream>>>(
        edges, a1, a2, WhB, bias1, state1B, S, cnt, accg, cnt2, W_out, b_out,
        (float*)d_out);
}